// Round 1
// baseline (296.573 us; speedup 1.0000x reference)
//
#include <hip/hip_runtime.h>
#include <cstdint>
#include <cstddef>

#define B_ROWS 16384
#define D_DIM  1024
#define F_REAL 1034          // real hidden/feature dim
#define N_PAD  1152          // 9 * 128
#define K_PAD  1088          // 1024 h + 10 scal + 54 zero  (17 * 64)
#define NK     (K_PAD / 64)  // 17 iterations of BK=64
#define EPSN   1e-12f

typedef __bf16 bf16x8 __attribute__((ext_vector_type(8)));
typedef float  f32x4  __attribute__((ext_vector_type(4)));
typedef unsigned short u16;

__device__ __forceinline__ u16 f2bf(float f) {
    __bf16 b = (__bf16)f;
    return __builtin_bit_cast(u16, b);
}

// -------------------------------------------------------------------------
// prep: HALF-row per wave (R1: was full row -> compiler serialized loads
// into 4 batches, VGPR=36 proved it; now 8 loads all in flight), 2 rows
// per 256-thread block, LDS combine for the row-scalar features.
// -------------------------------------------------------------------------
__global__ __launch_bounds__(256)
void prep_kernel(const float* __restrict__ h, const float* __restrict__ vp,
                 const float* __restrict__ vh, const float* __restrict__ nd,
                 const float* __restrict__ nsp, u16* __restrict__ A)
{
    __shared__ float red[4][8];
    const int tid  = threadIdx.x;
    const int wave = tid >> 6;
    const int lane = tid & 63;
    const int row  = blockIdx.x * 2 + (wave >> 1);
    const int half = wave & 1;
    const int base = half * 128;          // float4 index base within the row

    const float4* hp  = (const float4*)(h  + (size_t)row * D_DIM);
    const float4* vpp = (const float4*)(vp + (size_t)row * D_DIM);
    const float4* vhp = (const float4*)(vh + (size_t)row * D_DIM);
    const float4* ndp = (const float4*)nd;
    u16* arow = A + (size_t)row * K_PAD;

    // all 8 vector loads issued before any compute (sched_barrier pins them)
    float4 p0 = vpp[base + lane], p1 = vpp[base + 64 + lane];
    float4 q0 = vhp[base + lane], q1 = vhp[base + 64 + lane];
    float4 f0 = hp [base + lane], f1 = hp [base + 64 + lane];
    float4 n0 = ndp[base + lane], n1 = ndp[base + 64 + lane];
    float ns = nsp[0];
    __builtin_amdgcn_sched_barrier(0);

    float s_pp = p0.x*p0.x + p0.y*p0.y + p0.z*p0.z + p0.w*p0.w
               + p1.x*p1.x + p1.y*p1.y + p1.z*p1.z + p1.w*p1.w;
    float s_hh = q0.x*q0.x + q0.y*q0.y + q0.z*q0.z + q0.w*q0.w
               + q1.x*q1.x + q1.y*q1.y + q1.z*q1.z + q1.w*q1.w;
    float s_pv = p0.x*q0.x + p0.y*q0.y + p0.z*q0.z + p0.w*q0.w
               + p1.x*q1.x + p1.y*q1.y + p1.z*q1.z + p1.w*q1.w;
    float s_ff = f0.x*f0.x + f0.y*f0.y + f0.z*f0.z + f0.w*f0.w
               + f1.x*f1.x + f1.y*f1.y + f1.z*f1.z + f1.w*f1.w;
    float dx0 = q0.x-p0.x, dy0 = q0.y-p0.y, dz0 = q0.z-p0.z, dw0 = q0.w-p0.w;
    float dx1 = q1.x-p1.x, dy1 = q1.y-p1.y, dz1 = q1.z-p1.z, dw1 = q1.w-p1.w;
    float s_dd = dx0*dx0 + dy0*dy0 + dz0*dz0 + dw0*dw0
               + dx1*dx1 + dy1*dy1 + dz1*dz1 + dw1*dw1;
    float s_pn = p0.x*n0.x + p0.y*n0.y + p0.z*n0.z + p0.w*n0.w
               + p1.x*n1.x + p1.y*n1.y + p1.z*n1.z + p1.w*n1.w;
    float s_hn = q0.x*n0.x + q0.y*n0.y + q0.z*n0.z + q0.w*n0.w
               + q1.x*n1.x + q1.y*n1.y + q1.z*n1.z + q1.w*n1.w;
    float s_nn = n0.x*n0.x + n0.y*n0.y + n0.z*n0.z + n0.w*n0.w
               + n1.x*n1.x + n1.y*n1.y + n1.z*n1.z + n1.w*n1.w;

    // bf16 conversion store of this half of h
    ushort4 h0c, h1c;
    h0c.x = f2bf(f0.x); h0c.y = f2bf(f0.y); h0c.z = f2bf(f0.z); h0c.w = f2bf(f0.w);
    h1c.x = f2bf(f1.x); h1c.y = f2bf(f1.y); h1c.z = f2bf(f1.z); h1c.w = f2bf(f1.w);
    *(ushort4*)(arow + (base + lane) * 4)      = h0c;
    *(ushort4*)(arow + (base + 64 + lane) * 4) = h1c;

    #pragma unroll
    for (int m = 32; m >= 1; m >>= 1) {
        s_pp += __shfl_xor(s_pp, m, 64);
        s_hh += __shfl_xor(s_hh, m, 64);
        s_pv += __shfl_xor(s_pv, m, 64);
        s_ff += __shfl_xor(s_ff, m, 64);
        s_dd += __shfl_xor(s_dd, m, 64);
        s_pn += __shfl_xor(s_pn, m, 64);
        s_hn += __shfl_xor(s_hn, m, 64);
        s_nn += __shfl_xor(s_nn, m, 64);
    }

    if (lane == 0) {
        red[wave][0] = s_pp; red[wave][1] = s_hh; red[wave][2] = s_pv;
        red[wave][3] = s_ff; red[wave][4] = s_dd; red[wave][5] = s_pn;
        red[wave][6] = s_hn; red[wave][7] = s_nn;
    }
    __syncthreads();

    if (half == 0 && lane == 0) {
        const int ow = wave + 1;
        float t_pp = red[wave][0] + red[ow][0];
        float t_hh = red[wave][1] + red[ow][1];
        float t_pv = red[wave][2] + red[ow][2];
        float t_ff = red[wave][3] + red[ow][3];
        float t_dd = red[wave][4] + red[ow][4];
        float t_pn = red[wave][5] + red[ow][5];
        float t_hn = red[wave][6] + red[ow][6];
        float t_nn = red[wave][7] + red[ow][7];

        float np_ = sqrtf(t_pp), nh_ = sqrtf(t_hh), nf = sqrtf(t_ff);
        float npc = fmaxf(np_, EPSN), nhc = fmaxf(nh_, EPSN);
        float nnc = fmaxf(sqrtf(t_nn), EPSN);
        float align = t_pv / (npc * nhc);
        u16 fo[64];
        fo[0] = f2bf(align);
        fo[1] = f2bf(-align);
        fo[2] = f2bf(0.5f * (1.0f + align));      // K_O = 1
        fo[3] = f2bf(0.5f * (1.0f - align));
        fo[4] = f2bf(sqrtf(t_dd));
        fo[5] = f2bf(np_);
        fo[6] = f2bf(nh_);
        fo[7] = f2bf(nf);
        fo[8] = f2bf(ns * t_pn / (npc * nnc));
        fo[9] = f2bf(ns * t_hn / (nhc * nnc));
        #pragma unroll
        for (int i = 10; i < 64; ++i) fo[i] = 0;
        #pragma unroll
        for (int i = 0; i < 8; ++i)
            *(uint4*)(arow + D_DIM + i * 8) = *(uint4*)(fo + i * 8);
    }
}

// -------------------------------------------------------------------------
// w1 [1034x1034] f32 -> padded bf16 B^T matrix [1152 x 1088]
// -------------------------------------------------------------------------
__global__ __launch_bounds__(256)
void convw_kernel(const float* __restrict__ w1, u16* __restrict__ Bm)
{
    const int i = blockIdx.x;
    for (int j = threadIdx.x; j < K_PAD; j += 256) {
        float v = (i < F_REAL && j < F_REAL) ? w1[(size_t)i * F_REAL + j] : 0.0f;
        Bm[(size_t)i * K_PAD + j] = f2bf(v);
    }
}

// out[b*3+c] = b2[c]  (out is poisoned 0xAA each launch)
__global__ __launch_bounds__(256)
void initout_kernel(const float* __restrict__ b2, float* __restrict__ out)
{
    int i = blockIdx.x * 256 + threadIdx.x;
    if (i < B_ROWS * 3) out[i] = b2[i % 3];
}

// -------------------------------------------------------------------------
// GEMM1: R1 change -- 128x128 block tile, 64x64 WAVE tile (4x4 fragments).
// Old 32x64 wave tile was LDS-read-BW bound: MfmaUtil 20.4% == exactly the
// (M_w+N_w)/(M_w*N_w) LDS-byte/FLOP ceiling at 128 B/cyc. 64x64 halves LDS
// bytes/FLOP. Swizzle upgraded (row&3 -> (row>>1)&3): frag read now hits
// 8 distinct 16B slot-groups x2 = 2-way (free), was 4-way (1.58x).
// Depth-2 register pipeline, single LDS buffer, 2 barriers/K-tile kept.
// Fused bias+ReLU+GEMM2 epilogue -> atomic partial logits.
// -------------------------------------------------------------------------
__global__ __launch_bounds__(256, 2)
void gemm_kernel(const u16* __restrict__ A,
                 const u16* __restrict__ Bm,
                 const float* __restrict__ b1, const float* __restrict__ w2,
                 float* __restrict__ out)
{
    // two 32-k halves; slot layout (row*4 + (kc^((row>>1)&3)))*8
    __shared__ __bf16 As[2 * 128 * 32];   // 16 KB
    __shared__ __bf16 Bs[2 * 128 * 32];   // 16 KB

    const int tid  = threadIdx.x;
    const int lane = tid & 63;
    const int wave = tid >> 6;
    const int wm = wave >> 1, wn = wave & 1;   // wave covers 64(m) x 64(n)
    const int bm = blockIdx.x, bn = blockIdx.y;

    const int srow = tid >> 2;                         // 0..63
    const int kc   = (tid & 3) ^ ((srow >> 1) & 3);    // inverse swizzle on SRC
    const u16* gaA[2];
    const u16* gaB[2];
    __bf16 *lA[2], *lB[2];
    #pragma unroll
    for (int o = 0; o < 2; ++o) {
        gaA[o] = A  + (size_t)(bm * 128 + o * 64 + srow) * K_PAD + kc * 8;
        gaB[o] = Bm + (size_t)(bn * 128 + o * 64 + srow) * K_PAD + kc * 8;
        lA[o]  = As + (o * 256 + tid) * 8;   // linear LDS dest
        lB[o]  = Bs + (o * 256 + tid) * 8;
    }

    const int col  = lane & 15;
    const int quad = lane >> 4;
    const int swz  = quad ^ ((col >> 1) & 3);
    int aoff[4], boff[4];
    #pragma unroll
    for (int i = 0; i < 4; ++i)
        aoff[i] = ((wm * 64 + i * 16 + col) * 4 + swz) * 8;
    #pragma unroll
    for (int j = 0; j < 4; ++j)
        boff[j] = ((wn * 64 + j * 16 + col) * 4 + swz) * 8;

    f32x4 acc[4][4];
    #pragma unroll
    for (int i = 0; i < 4; ++i)
        #pragma unroll
        for (int j = 0; j < 4; ++j)
            acc[i][j] = (f32x4){0.f, 0.f, 0.f, 0.f};

    // two register stages; tile t lives in stage t&1
    uint4 a0_0, a0_1, a0_2, a0_3, b0_0, b0_1, b0_2, b0_3;
    uint4 a1_0, a1_1, a1_2, a1_3, b1_0, b1_1, b1_2, b1_3;

#define LOAD_STAGE(st, ko)                                                    \
    do {                                                                      \
        a##st##_0 = *(const uint4*)(gaA[0] + (ko));                           \
        a##st##_1 = *(const uint4*)(gaA[0] + (ko) + 32);                      \
        a##st##_2 = *(const uint4*)(gaA[1] + (ko));                           \
        a##st##_3 = *(const uint4*)(gaA[1] + (ko) + 32);                      \
        b##st##_0 = *(const uint4*)(gaB[0] + (ko));                           \
        b##st##_1 = *(const uint4*)(gaB[0] + (ko) + 32);                      \
        b##st##_2 = *(const uint4*)(gaB[1] + (ko));                           \
        b##st##_3 = *(const uint4*)(gaB[1] + (ko) + 32);                      \
    } while (0)

#define WRITE_STAGE(st)                                                       \
    do {                                                                      \
        *(uint4*)(lA[0])        = a##st##_0;                                  \
        *(uint4*)(lA[0] + 4096) = a##st##_1;                                  \
        *(uint4*)(lA[1])        = a##st##_2;                                  \
        *(uint4*)(lA[1] + 4096) = a##st##_3;                                  \
        *(uint4*)(lB[0])        = b##st##_0;                                  \
        *(uint4*)(lB[0] + 4096) = b##st##_1;                                  \
        *(uint4*)(lB[1])        = b##st##_2;                                  \
        *(uint4*)(lB[1] + 4096) = b##st##_3;                                  \
    } while (0)

#define COMPUTE_TILE                                                          \
    do {                                                                      \
        _Pragma("unroll")                                                     \
        for (int hh = 0; hh < 2; ++hh) {                                      \
            const __bf16* Ab = As + hh * 4096;                                \
            const __bf16* Bb = Bs + hh * 4096;                                \
            bf16x8 av[4], bv[4];                                              \
            _Pragma("unroll")                                                 \
            for (int i = 0; i < 4; ++i) av[i] = *(const bf16x8*)(Ab + aoff[i]); \
            _Pragma("unroll")                                                 \
            for (int j = 0; j < 4; ++j) bv[j] = *(const bf16x8*)(Bb + boff[j]); \
            _Pragma("unroll")                                                 \
            for (int i = 0; i < 4; ++i)                                       \
                _Pragma("unroll")                                             \
                for (int j = 0; j < 4; ++j)                                   \
                    acc[i][j] = __builtin_amdgcn_mfma_f32_16x16x32_bf16(      \
                                    av[i], bv[j], acc[i][j], 0, 0, 0);        \
        }                                                                     \
    } while (0)

    // prologue: t0 -> S0, t1 -> S1 (both in flight), write t0, sync
    LOAD_STAGE(0, 0);
    LOAD_STAGE(1, 64);
    WRITE_STAGE(0);
    __syncthreads();

    for (int kt = 0; kt < NK; kt += 2) {
        // even sub-iter kt: prefetch t(kt+2) -> S0; write t(kt+1) from S1
        if (kt + 2 < NK) LOAD_STAGE(0, (kt + 2) * 64);
        COMPUTE_TILE;
        if (kt + 1 < NK) {
            __syncthreads();
            WRITE_STAGE(1);
            __syncthreads();

            // odd sub-iter kt+1: prefetch t(kt+3) -> S1; write t(kt+2) from S0
            if (kt + 3 < NK) LOAD_STAGE(1, (kt + 3) * 64);
            COMPUTE_TILE;
            if (kt + 2 < NK) {
                __syncthreads();
                WRITE_STAGE(0);
                __syncthreads();
            }
        }
    }

    // epilogue: hidden = relu(acc + b1[n]); logits partial = hidden @ w2^T
    float bias[4], w20[4], w21[4], w22[4];
    #pragma unroll
    for (int ni = 0; ni < 4; ++ni) {
        int n = bn * 128 + wn * 64 + ni * 16 + col;
        bool v = n < F_REAL;   // padded rows have acc==0 anyway
        bias[ni] = v ? b1[n] : 0.0f;
        w20[ni]  = v ? w2[n] : 0.0f;
        w21[ni]  = v ? w2[F_REAL + n] : 0.0f;
        w22[ni]  = v ? w2[2 * F_REAL + n] : 0.0f;
    }
    #pragma unroll
    for (int mi = 0; mi < 4; ++mi) {
        float c0[4] = {0,0,0,0}, c1[4] = {0,0,0,0}, c2[4] = {0,0,0,0};
        #pragma unroll
        for (int ni = 0; ni < 4; ++ni) {
            #pragma unroll
            for (int r = 0; r < 4; ++r) {
                float hd = fmaxf(acc[mi][ni][r] + bias[ni], 0.0f);
                c0[r] += hd * w20[ni];
                c1[r] += hd * w21[ni];
                c2[r] += hd * w22[ni];
            }
        }
        #pragma unroll
        for (int m = 8; m >= 1; m >>= 1) {
            #pragma unroll
            for (int r = 0; r < 4; ++r) {
                c0[r] += __shfl_xor(c0[r], m, 64);
                c1[r] += __shfl_xor(c1[r], m, 64);
                c2[r] += __shfl_xor(c2[r], m, 64);
            }
        }
        if (col == 0) {
            int gm = bm * 128 + wm * 64 + mi * 16 + quad * 4;
            #pragma unroll
            for (int r = 0; r < 4; ++r) {
                atomicAdd(out + (size_t)(gm + r) * 3 + 0, c0[r]);
                atomicAdd(out + (size_t)(gm + r) * 3 + 1, c1[r]);
                atomicAdd(out + (size_t)(gm + r) * 3 + 2, c2[r]);
            }
        }
    }
}

extern "C" void kernel_launch(void* const* d_in, const int* in_sizes, int n_in,
                              void* d_out, int out_size, void* d_ws, size_t ws_size,
                              hipStream_t stream)
{
    const float* h  = (const float*)d_in[0];
    const float* vp = (const float*)d_in[1];
    const float* vh = (const float*)d_in[2];
    const float* nd = (const float*)d_in[3];
    const float* ns = (const float*)d_in[4];
    const float* w1 = (const float*)d_in[5];
    const float* b1 = (const float*)d_in[6];
    const float* w2 = (const float*)d_in[7];
    const float* b2 = (const float*)d_in[8];
    float* out = (float*)d_out;

    u16* Afull = (u16*)d_ws;                              // [16384][1088] bf16
    u16* Bfull = Afull + (size_t)B_ROWS * K_PAD;          // [1152][1088]  bf16

    prep_kernel<<<B_ROWS / 2, 256, 0, stream>>>(h, vp, vh, nd, ns, Afull);
    convw_kernel<<<N_PAD, 256, 0, stream>>>(w1, Bfull);
    initout_kernel<<<(B_ROWS * 3 + 255) / 256, 256, 0, stream>>>(b2, out);
    gemm_kernel<<<dim3(B_ROWS / 128, N_PAD / 128), 256, 0, stream>>>(
        Afull, Bfull, b1, w2, out);
}